// Round 6
// baseline (3706.006 us; speedup 1.0000x reference)
//
#include <hip/hip_runtime.h>
#include <hip/hip_bf16.h>
#include <cmath>

typedef __attribute__((ext_vector_type(8))) short short8;   // 8 bf16 = 4 VGPRs
typedef __attribute__((ext_vector_type(4))) float floatx4;  // MFMA 16x16 accumulator

#define TS   512
#define DIM  1024
#define HD   1024
#define KTOT 2048
#define GRID_BLOCKS 256
#define XSTRIDE 1032                  // LDS row stride (bf16): 2064B (proven layout)
#define ROWSTRIDE ((size_t)TS * HD)   // batch-row stride of x and out (elements)

// ---------------------------------------------------------------------------
// One-time transpose + fp32->bf16: WT[j][k] = bf16( k<1024 ? Wx[k][j] : Wh[k-1024][j] )
// ---------------------------------------------------------------------------
__global__ void build_wt(const float* __restrict__ Wx,
                         const float* __restrict__ Wh,
                         __hip_bfloat16* __restrict__ WT) {
    __shared__ __hip_bfloat16 tile[32][33];
    const int j0 = blockIdx.x * 32;
    const int k0 = blockIdx.y * 32;
    const int tx = threadIdx.x & 31;
    const int ty = threadIdx.x >> 5;
    #pragma unroll
    for (int kk = 0; kk < 32; kk += 8) {
        const int k = k0 + ty + kk;
        const float* S = (k < DIM) ? (Wx + (size_t)k * 4096)
                                   : (Wh + (size_t)(k - DIM) * 4096);
        tile[ty + kk][tx] = __float2bfloat16(S[j0 + tx]);
    }
    __syncthreads();
    #pragma unroll
    for (int kk = 0; kk < 32; kk += 8) {
        const int j = j0 + ty + kk;
        WT[(size_t)j * KTOT + k0 + tx] = tile[tx][ty + kk];
    }
}

// fast sigmoid/tanh: v_exp_f32 + v_rcp_f32 (~1e-6 rel err, << bf16 noise)
__device__ __forceinline__ float fast_sig(float x) {
    return __builtin_amdgcn_rcpf(1.0f + __expf(-x));
}
__device__ __forceinline__ float fast_tanh(float x) {
    return 1.0f - 2.0f * __builtin_amdgcn_rcpf(1.0f + __expf(2.0f * x));
}

// ---------------------------------------------------------------------------
// Persistent LSTM scan — tagged self-sync (round-3 protocol) with a
// shortened post-detect path:
//   * x-half MFMA runs BEFORE the poll (overlaps publish flight / arrival)
//   * gate exchange via in-register 4x4 shfl_xor transpose (no lds_g, no S2)
//   * Bh double-buffered -> ONE __syncthreads per step
//
// A-operand repartition: wave w's 16 A-rows are {gate g, col j0+4w+(m&3)}
// for m=0..15, g=m>>2. After MFMA, lane (f=lane&15, q=lane>>4) reg r holds
// gate q, col-offset r. A 4x4 butterfly transpose across lanes f+16q
// (xor 16, then xor 32) gives lane (f,q) all 4 gates of output
// (n0+f, j0+4w+q) -> epilogue is lane-local.
//
// Tag protocol (proven R3): hbuf32[parity][n*1024+j] = (bf16(h)<<16)|tag,
// tag=t+1, parity=t&1. Producer: one relaxed agent store, fire & forget.
// Consumer: monolithic poll, detecting load IS the data load. Overwrite
// safety: publishing tag t+2 requires having seen tag t+1 from all peers,
// which transitively implies all readers finished with tag t-1 content.
// ---------------------------------------------------------------------------
__global__ __launch_bounds__(256, 1)
void lstm_scan(const float* __restrict__ x,
               const float* __restrict__ h0,
               const __hip_bfloat16* __restrict__ WT,
               const float* __restrict__ bias,
               float* __restrict__ out,
               unsigned* __restrict__ hbuf32) {   // 2 * 65536 tagged words
    __shared__ __hip_bfloat16 XB[2][16][XSTRIDE];  // x_t, double-buffered
    __shared__ __hip_bfloat16 Bh[2][16][XSTRIDE];  // h_{t-1}, double-buffered

    const int blk  = blockIdx.x;
    const int ng   = (blk >> 1) & 3;                    // XCD-pair group
    const int cs   = ((blk >> 3) << 1) | (blk & 1);     // 0..63 within group
    const int tid  = threadIdx.x;
    const int wave = tid >> 6;
    const int lane = tid & 63;
    const int n0 = ng * 16;
    const int j0 = cs * 16;

    const int frag_m = lane & 15;        // A-row index m / B: batch row n
    const int frag_k = (lane >> 4) * 8;  // k sub-offset within 32-chunk
    const int q      = lane >> 4;        // 0..3

    // ---- publish h0 ASAP (tag 1, parity 0), grid-flat coalesced ----
    const int flat = blk * 256 + tid;    // 0..65535 == n*1024+j
    {
        const unsigned w0 =
            ((unsigned)(unsigned short)__bfloat16_as_short(__float2bfloat16(h0[flat])) << 16) | 1u;
        __hip_atomic_store(hbuf32 + flat, w0,
                           __ATOMIC_RELAXED, __HIP_MEMORY_SCOPE_AGENT);
    }

    // ---- preload this wave's A fragments (gate-mixed row map) ----
    // A-row m -> WT row (m>>2)*HD + j0 + 4*wave + (m&3)
    const int arow = ((frag_m >> 2) * HD) + j0 + 4 * wave + (frag_m & 3);
    const __hip_bfloat16* wrow = WT + (size_t)arow * KTOT + frag_k;
    short8 wreg[64];
    #pragma unroll
    for (int i = 0; i < 32; ++i)
        wreg[i] = *(const short8*)(wrow + i * 32);
    #pragma unroll
    for (int i = 0; i < 32; ++i)
        wreg[32 + i] = *(const short8*)(wrow + DIM + i * 32);

    // ---- stage x_0 -> XB[0] ----
    #pragma unroll
    for (int j = 0; j < 8; ++j) {
        const int c = j * 256 + tid;
        const int r = c >> 7;
        const int col = (c & 127) * 8;
        const float* xs = x + (size_t)(n0 + r) * ROWSTRIDE + col;
        float4 f0 = *(const float4*)xs;
        float4 f1 = *(const float4*)(xs + 4);
        short8 v;
        v[0] = __bfloat16_as_short(__float2bfloat16(f0.x));
        v[1] = __bfloat16_as_short(__float2bfloat16(f0.y));
        v[2] = __bfloat16_as_short(__float2bfloat16(f0.z));
        v[3] = __bfloat16_as_short(__float2bfloat16(f0.w));
        v[4] = __bfloat16_as_short(__float2bfloat16(f1.x));
        v[5] = __bfloat16_as_short(__float2bfloat16(f1.y));
        v[6] = __bfloat16_as_short(__float2bfloat16(f1.z));
        v[7] = __bfloat16_as_short(__float2bfloat16(f1.w));
        *(short8*)&XB[0][r][col] = v;
    }
    __syncthreads();   // S0: XB[0] visible to all waves

    // ---- per-lane epilogue constants ----
    const int jl = j0 + 4 * wave + q;        // this lane's output column
    const int nl = n0 + frag_m;              // this lane's batch row
    float c_reg = 0.0f;
    const float bi  = bias[         jl];
    const float bf_ = bias[1 * HD + jl];
    const float bo  = bias[2 * HD + jl];
    const float bg  = bias[3 * HD + jl];
    float* out_e = out + (size_t)nl * ROWSTRIDE + jl;
    const int hb_idx = nl * 1024 + jl;

    for (int t = 0; t < TS; ++t) {
        const int par = t & 1;
        const int nxt = (t + 1) & 1;

        // ---- (A) issue x_{t+1} loads; in flight during poll ----
        float4 xf[16];
        if (t + 1 < TS) {
            #pragma unroll
            for (int j = 0; j < 8; ++j) {
                const int c = j * 256 + tid;
                const int r = c >> 7;
                const int col = (c & 127) * 8;
                const float* xs = x + (size_t)(n0 + r) * ROWSTRIDE
                                    + (size_t)(t + 1) * DIM + col;
                xf[2 * j]     = *(const float4*)xs;
                xf[2 * j + 1] = *(const float4*)(xs + 4);
            }
        }

        // ---- (B) x-half MFMA from XB[par] — BEFORE the poll, so this
        //      LDS+MFMA work overlaps peers' publish flight ----
        floatx4 a0 = {0.f, 0.f, 0.f, 0.f};
        floatx4 a1 = {0.f, 0.f, 0.f, 0.f};
        #pragma unroll
        for (int i = 0; i < 32; i += 2) {
            short8 b8a = *(const short8*)&XB[par][frag_m][i * 32 + frag_k];
            short8 b8b = *(const short8*)&XB[par][frag_m][(i + 1) * 32 + frag_k];
            a0 = __builtin_amdgcn_mfma_f32_16x16x32_bf16(wreg[i],     b8a, a0, 0, 0, 0);
            a1 = __builtin_amdgcn_mfma_f32_16x16x32_bf16(wreg[i + 1], b8b, a1, 0, 0, 0);
        }
        __builtin_amdgcn_sched_barrier(0);   // keep x-MFMA ahead of the poll

        // ---- (P) monolithic poll: detecting load IS the data (R3-proven) ----
        const unsigned long long* pb =
            (const unsigned long long*)hbuf32 + ((size_t)par << 15);
        const unsigned long long tagpat =
            (unsigned long long)(unsigned)(t + 1)
            | ((unsigned long long)(unsigned)(t + 1) << 32);
        unsigned long long hb[32];
        bool ok;
        do {
            ok = true;
            #pragma unroll
            for (int j = 0; j < 8; ++j) {
                const int c = j * 256 + tid;
                const int r = c >> 7;
                const int col = (c & 127) * 8;
                const size_t o = (size_t)(((n0 + r) << 10) + col) >> 1;
                #pragma unroll
                for (int qq = 0; qq < 4; ++qq)
                    hb[4 * j + qq] = __hip_atomic_load(pb + o + qq,
                        __ATOMIC_RELAXED, __HIP_MEMORY_SCOPE_AGENT);
            }
            #pragma unroll
            for (int k = 0; k < 32; ++k)
                ok = ok && ((hb[k] & 0x0000FFFF0000FFFFull) == tagpat);
        } while (!__all((int)ok));

        // ---- (C) extract bf16 (high halves) -> Bh[par] ----
        #pragma unroll
        for (int j = 0; j < 8; ++j) {
            const int c = j * 256 + tid;
            const int r = c >> 7;
            const int col = (c & 127) * 8;
            short8 v;
            #pragma unroll
            for (int qq = 0; qq < 4; ++qq) {
                const unsigned long long u = hb[4 * j + qq];
                v[2 * qq]     = (short)(unsigned short)(u >> 16);
                v[2 * qq + 1] = (short)(unsigned short)(u >> 48);
            }
            *(short8*)&Bh[par][r][col] = v;
        }

        // ---- (D) convert & park x_{t+1} -> XB[nxt] ----
        if (t + 1 < TS) {
            #pragma unroll
            for (int j = 0; j < 8; ++j) {
                const int c = j * 256 + tid;
                const int r = c >> 7;
                const int col = (c & 127) * 8;
                const float4 f0 = xf[2 * j];
                const float4 f1 = xf[2 * j + 1];
                short8 v;
                v[0] = __bfloat16_as_short(__float2bfloat16(f0.x));
                v[1] = __bfloat16_as_short(__float2bfloat16(f0.y));
                v[2] = __bfloat16_as_short(__float2bfloat16(f0.z));
                v[3] = __bfloat16_as_short(__float2bfloat16(f0.w));
                v[4] = __bfloat16_as_short(__float2bfloat16(f1.x));
                v[5] = __bfloat16_as_short(__float2bfloat16(f1.y));
                v[6] = __bfloat16_as_short(__float2bfloat16(f1.z));
                v[7] = __bfloat16_as_short(__float2bfloat16(f1.w));
                *(short8*)&XB[nxt][r][col] = v;
            }
        }
        __syncthreads();   // S1: the ONLY barrier per step.
        // Hazards covered: Bh[par] writes (C) before S1, reads (H) after;
        // XB[nxt] writes (D) before S1, reads next iter after it;
        // all XB[par]/Bh[par] reads of iter t-1 completed before S1(t-1)<S1(t).

        // ---- (H) h-half MFMA from Bh[par] ----
        floatx4 a2 = {0.f, 0.f, 0.f, 0.f};
        floatx4 a3 = {0.f, 0.f, 0.f, 0.f};
        #pragma unroll
        for (int i = 0; i < 32; i += 2) {
            short8 b8a = *(const short8*)&Bh[par][frag_m][i * 32 + frag_k];
            short8 b8b = *(const short8*)&Bh[par][frag_m][(i + 1) * 32 + frag_k];
            a2 = __builtin_amdgcn_mfma_f32_16x16x32_bf16(wreg[32 + i], b8a, a2, 0, 0, 0);
            a3 = __builtin_amdgcn_mfma_f32_16x16x32_bf16(wreg[33 + i], b8b, a3, 0, 0, 0);
        }
        floatx4 acc = (a0 + a1) + (a2 + a3);

        // ---- in-register 4x4 transpose across lanes f+16q (no LDS, no S2).
        //      Before: lane (f,q) reg r = gate q, col-offset r.
        //      After:  lane (f,q) reg g = gate g, col-offset q. ----
        float a[4] = {acc[0], acc[1], acc[2], acc[3]};
        {   // stage 1: xor 16 (q bit 0)
            float s0 = (q & 1) ? a[0] : a[1];
            float r0 = __shfl_xor(s0, 16);
            if (q & 1) a[0] = r0; else a[1] = r0;
            float s1 = (q & 1) ? a[2] : a[3];
            float r1 = __shfl_xor(s1, 16);
            if (q & 1) a[2] = r1; else a[3] = r1;
        }
        {   // stage 2: xor 32 (q bit 1)
            float s0 = (q & 2) ? a[0] : a[2];
            float r0 = __shfl_xor(s0, 32);
            if (q & 2) a[0] = r0; else a[2] = r0;
            float s1 = (q & 2) ? a[1] : a[3];
            float r1 = __shfl_xor(s1, 32);
            if (q & 2) a[1] = r1; else a[3] = r1;
        }

        // ---- gates + state update (lane-local, fast math) ----
        const float i_g = fast_sig(a[0] + bi);
        const float f_g = fast_sig(a[1] + bf_);
        const float o_g = fast_sig(a[2] + bo);
        const float g_g = fast_tanh(a[3] + bg);
        c_reg = f_g * c_reg + i_g * g_g;
        const float h = o_g * fast_tanh(c_reg);

        // ---- publish tagged h: ONE fire-and-forget store, ASAP ----
        if (t + 1 < TS) {
            const unsigned wrd =
                ((unsigned)(unsigned short)__bfloat16_as_short(__float2bfloat16(h)) << 16)
                | (unsigned)(t + 2);
            __hip_atomic_store(hbuf32 + (((size_t)nxt) << 16) + hb_idx, wrd,
                               __ATOMIC_RELAXED, __HIP_MEMORY_SCOPE_AGENT);
        }

        // fp32 output — fire-and-forget
        out_e[(size_t)t * HD] = h;
    }
}

// ---------------------------------------------------------------------------
extern "C" void kernel_launch(void* const* d_in, const int* in_sizes, int n_in,
                              void* d_out, int out_size, void* d_ws, size_t ws_size,
                              hipStream_t stream) {
    const float* x  = (const float*)d_in[0];
    const float* h0 = (const float*)d_in[1];
    const float* Wx = (const float*)d_in[2];
    const float* Wh = (const float*)d_in[3];
    const float* b  = (const float*)d_in[4];
    float* out = (float*)d_out;

    char* ws = (char*)d_ws;
    __hip_bfloat16* WT     = (__hip_bfloat16*)ws;              // 16 MiB
    unsigned*       hbuf32 = (unsigned*)(ws + (16u << 20));    // 512 KiB (2 x 65536 x 4B)

    hipMemsetAsync(hbuf32, 0, 2 * 65536 * sizeof(unsigned), stream);  // kill stale tags
    build_wt<<<dim3(128, 64), 256, 0, stream>>>(Wx, Wh, WT);
    lstm_scan<<<GRID_BLOCKS, 256, 0, stream>>>(x, h0, WT, b, out, hbuf32);
}